// Round 12
// baseline (192.649 us; speedup 1.0000x reference)
//
#include <hip/hip_runtime.h>
#include <hip/hip_bf16.h>

typedef __attribute__((ext_vector_type(4))) float f32x4;
typedef __attribute__((ext_vector_type(8))) short bf16x8;

#define H 1024        // hidden / K
#define NTOT 1280     // nq*64 + nkv*64*2
#define BM 128
#define BN 128
#define BK 64
#define NKT 16        // H / BK
#define NTILES 10     // NTOT / BN

static __device__ __forceinline__ unsigned short f2bf(float f) {
    __hip_bfloat16 b = __float2bfloat16(f);
    return __builtin_bit_cast(unsigned short, b);
}

#define GLOAD_LDS16(g, l)                                                     \
    __builtin_amdgcn_global_load_lds(                                         \
        (const __attribute__((address_space(1))) void*)(g),                   \
        (__attribute__((address_space(3))) void*)(l), 16, 0, 0)

// ---------------------------------------------------------------------------
// Kernel 1: Bt[n][k] = bf16((1+lnw[k]) * W[k][n]) via LDS transpose tile.
// ---------------------------------------------------------------------------
__global__ __launch_bounds__(256) void k_wprep(const float* __restrict__ wq,
                                               const float* __restrict__ wk,
                                               const float* __restrict__ wv,
                                               const float* __restrict__ lnw,
                                               __hip_bfloat16* __restrict__ Bt) {
    __shared__ float l[64][65];
    const int t = threadIdx.x;
    const int kt = blockIdx.x & 15;          // 16 k-tiles
    const int ntl = blockIdx.x >> 4;         // 20 n-tiles
    const int k0 = kt * 64, n0 = ntl * 64;
    const float* src; int ldn, nb;
    if (n0 < 1024)      { src = wq; ldn = 1024; nb = n0; }
    else if (n0 < 1152) { src = wk; ldn = 128;  nb = n0 - 1024; }
    else                { src = wv; ldn = 128;  nb = n0 - 1152; }
    const int nl = t & 63, kl = t >> 6;
#pragma unroll
    for (int i = 0; i < 16; ++i) {
        const int k = kl + i * 4;
        l[k][nl] = (1.0f + lnw[k0 + k]) * src[(size_t)(k0 + k) * ldn + nb + nl];
    }
    __syncthreads();
    const int k2 = t & 63, n2 = t >> 6;
#pragma unroll
    for (int i = 0; i < 16; ++i) {
        const int n = n2 + i * 4;
        Bt[(size_t)(n0 + n) * 1024 + k0 + k2] = __float2bfloat16(l[k2][n]);
    }
}

// ---------------------------------------------------------------------------
// Kernel 2: FUSED RMSNorm + QKV GEMM (R12).
// out = diag(rsqrt(mean(x^2)+eps)) . (bf16(x) @ Bt^T); scale applied in the
// epilogue (commutes with the linear map); sum(x^2) accumulated in-flight.
// R10's proven skeleton: 128x128 tile, 256 thr (4 waves 2x2), 64KB LDS
// ring-2, 2 blocks/CU (epilogue overlaps other block's K-loop), T2
// both-sides swizzle, XCD chunking nt-fastest, grid 2560 = 5 exact rounds.
// Fusion ledger (fixes R5/R6/R7 failures):
//   - acc[4][4]=64 AGPR + va[8]=32 VGPR transit -> ~175 unified regs, no
//     spill at launch_bounds(256,2)  [R5 failed: 128 AGPR + transit > 256]
//   - x(kt+2) issued at tile START, cvt+ds_write at tile END -> load lead
//     ~1 full tile (~3000 cyc) >> 900 cyc HBM latency  [R7 failed: 1 phase]
//   - vmcnt(4) at end-of-tile forces x(kt+2)+B(kt+1), keeps B(kt+2) in
//     flight; buffer writes strictly after the mid-tile barrier that
//     retires all reads of that buffer (race-free as R10).
// ---------------------------------------------------------------------------
__global__ __launch_bounds__(256, 2) void k_gemm(const float* __restrict__ X,
                                                 const __hip_bfloat16* __restrict__ Bt,
                                                 float* __restrict__ out, int rows) {
    __shared__ __align__(16) char smem[65536];  // 2 bufs x (A 16KB | B 16KB)
    __shared__ float s_lds[BM];

    const int tid = threadIdx.x;
    const int lane = tid & 63;
    const int wid = tid >> 6;
    const int wm = wid >> 1;   // 0..1 (64 rows each)
    const int wn = wid & 1;    // 0..1 (64 cols each)

    // bijective XCD chunk swizzle (2560 % 8 == 0), nt fastest (10 sharers
    // of each x-strip co-resident on one XCD's L2)
    const int cpx = gridDim.x >> 3;                 // 320
    const int wg = (blockIdx.x & 7) * cpx + (blockIdx.x >> 3);
    const int nt = wg % NTILES;
    const int mt = wg / NTILES;
    const size_t m0 = (size_t)mt * BM;

    // ---- A staging (fused): thread t covers rows rA+q*32 (q=0..3),
    //      fp32 cols (t&7)*8..+8 of each K-tile. ds_write swizzled.
    const int rA = tid >> 3;                        // 0..31
    const float* xb = X + (m0 + rA) * (size_t)H + (tid & 7) * 8;
    const int awz = ((tid & 7) * 16) ^ ((rA & 7) << 4);

    // ---- B staging: gload_lds, source col pre-swizzled (both-sides) ----
    const char* bG = (const char*)Bt + ((size_t)nt * BN + rA) * (size_t)(H * 2)
                     + (((tid & 7) * 16) ^ ((rA & 7) << 4));

    float4 va[8];
    float ssq[4] = {0.f, 0.f, 0.f, 0.f};

#define A_ISSUE(kt)                                                           \
    _Pragma("unroll") for (int q = 0; q < 4; ++q) {                           \
        va[q * 2]     = *(const float4*)(xb + (size_t)q * 32 * H + (kt) * 64);\
        va[q * 2 + 1] = *(const float4*)(xb + (size_t)q * 32 * H + (kt) * 64 + 4); \
    }

#define A_CVT(buf)                                                            \
    _Pragma("unroll") for (int q = 0; q < 4; ++q) {                           \
        float4 f0 = va[q * 2], f1 = va[q * 2 + 1];                            \
        ssq[q] += f0.x * f0.x + f0.y * f0.y + f0.z * f0.z + f0.w * f0.w;      \
        ssq[q] += f1.x * f1.x + f1.y * f1.y + f1.z * f1.z + f1.w * f1.w;      \
        bf16x8 pk;                                                            \
        pk[0] = f2bf(f0.x); pk[1] = f2bf(f0.y); pk[2] = f2bf(f0.z);           \
        pk[3] = f2bf(f0.w); pk[4] = f2bf(f1.x); pk[5] = f2bf(f1.y);           \
        pk[6] = f2bf(f1.z); pk[7] = f2bf(f1.w);                               \
        *(bf16x8*)(smem + (buf) * 32768 + rA * 128 + q * 4096 + awz) = pk;    \
    }

#define STAGE_B(buf, kt)                                                      \
    _Pragma("unroll") for (int q = 0; q < 4; ++q)                             \
        GLOAD_LDS16(bG + (size_t)(kt) * 128 + (size_t)q * 32 * (H * 2),       \
                    smem + (buf) * 32768 + 16384 + q * 4096 + tid * 16);

    // ---- fragment read addressing (swizzled) ----
    const int rowA = wm * 64 + (lane & 15);
    const int rowB = wn * 64 + (lane & 15);
    const int xm = (lane & 7) << 4;
    const int c0 = (((lane >> 4) * 16)) ^ xm;
    const int c1 = (64 + ((lane >> 4) * 16)) ^ xm;

    f32x4 acc[4][4] = {};

#define TILE(cur, kt, DS, TAIL)                                               \
    {                                                                         \
        const char* aL = smem + (cur) * 32768;                                \
        const char* bL = aL + 16384;                                          \
        if (DS) A_ISSUE((kt) + 2);                                            \
        bf16x8 a0[4], b0[4];                                                  \
        _Pragma("unroll") for (int mi = 0; mi < 4; ++mi)                      \
            a0[mi] = *(const bf16x8*)(aL + (rowA + mi * 16) * 128 + c0);      \
        _Pragma("unroll") for (int ni = 0; ni < 4; ++ni)                      \
            b0[ni] = *(const bf16x8*)(bL + (rowB + ni * 16) * 128 + c0);      \
        asm volatile("s_waitcnt lgkmcnt(0)" ::: "memory");                    \
        __builtin_amdgcn_s_setprio(1);                                        \
        _Pragma("unroll") for (int mi = 0; mi < 4; ++mi)                      \
            _Pragma("unroll") for (int ni = 0; ni < 4; ++ni)                  \
                acc[mi][ni] = __builtin_amdgcn_mfma_f32_16x16x32_bf16(        \
                    a0[mi], b0[ni], acc[mi][ni], 0, 0, 0);                    \
        __builtin_amdgcn_s_setprio(0);                                        \
        bf16x8 a1[4], b1[4];                                                  \
        _Pragma("unroll") for (int mi = 0; mi < 4; ++mi)                      \
            a1[mi] = *(const bf16x8*)(aL + (rowA + mi * 16) * 128 + c1);      \
        _Pragma("unroll") for (int ni = 0; ni < 4; ++ni)                      \
            b1[ni] = *(const bf16x8*)(bL + (rowB + ni * 16) * 128 + c1);      \
        asm volatile("s_waitcnt lgkmcnt(0)" ::: "memory");                    \
        __builtin_amdgcn_s_barrier();        /* all reads of buf cur done */  \
        __builtin_amdgcn_sched_barrier(0);                                    \
        if (DS) {                                                             \
            STAGE_B(cur, (kt) + 2);                                           \
            asm volatile("s_waitcnt vmcnt(4)" ::: "memory");                  \
            A_CVT(cur);                                                       \
        }                                                                     \
        if (TAIL) asm volatile("s_waitcnt vmcnt(0)" ::: "memory");            \
        __builtin_amdgcn_s_setprio(1);                                        \
        _Pragma("unroll") for (int mi = 0; mi < 4; ++mi)                      \
            _Pragma("unroll") for (int ni = 0; ni < 4; ++ni)                  \
                acc[mi][ni] = __builtin_amdgcn_mfma_f32_16x16x32_bf16(        \
                    a1[mi], b1[ni], acc[mi][ni], 0, 0, 0);                    \
        __builtin_amdgcn_s_setprio(0);                                        \
        asm volatile("s_waitcnt lgkmcnt(0)" ::: "memory");                    \
        __builtin_amdgcn_sched_barrier(0);                                    \
        __builtin_amdgcn_s_barrier();                                         \
        __builtin_amdgcn_sched_barrier(0);                                    \
    }

    // ---- prologue: build tiles 0 (buf0) and 1 (buf1) ----
    A_ISSUE(0);
    STAGE_B(0, 0);
    asm volatile("s_waitcnt vmcnt(4)" ::: "memory");   // x(0) done
    A_CVT(0);
    A_ISSUE(1);
    STAGE_B(1, 1);
    asm volatile("s_waitcnt vmcnt(4)" ::: "memory");   // B(0), x(1) done
    A_CVT(1);
    asm volatile("s_waitcnt lgkmcnt(0)" ::: "memory");
    __builtin_amdgcn_sched_barrier(0);
    __builtin_amdgcn_s_barrier();
    __builtin_amdgcn_sched_barrier(0);

    // ---- main loop: ring-2, 2 barriers/tile ----
    for (int kt = 0; kt < 14; kt += 2) {
        TILE(0, kt, 1, 0);
        TILE(1, kt + 1, 1, 0);
    }
    TILE(0, 14, 0, 1);    // vmcnt(0): drain B(15)
    TILE(1, 15, 0, 0);

    // ---- row scales: 8 staging lanes per row hold partial sum(x^2) ----
#pragma unroll
    for (int q = 0; q < 4; ++q) {
        float s = ssq[q];
        s += __shfl_xor(s, 1);
        s += __shfl_xor(s, 2);
        s += __shfl_xor(s, 4);
        if ((tid & 7) == 0) s_lds[rA + q * 32] = rsqrtf(s * (1.0f / H) + 1e-6f);
    }
    __syncthreads();

    // ---- epilogue: scale rows, split q/k/v regions ----
    const size_t QSZ = (size_t)rows * 1024;
    const size_t KSZ = (size_t)rows * 128;
    const int colg0 = nt * BN + wn * 64;
    float* op;
    int ldc, cb0;
    if (colg0 < 1024)      { op = out;             ldc = 1024; cb0 = colg0; }
    else if (colg0 < 1152) { op = out + QSZ;       ldc = 128;  cb0 = colg0 - 1024; }
    else                   { op = out + QSZ + KSZ; ldc = 128;  cb0 = colg0 - 1152; }

    const int rl0 = wm * 64 + ((lane >> 4) * 4);
    const size_t r0 = m0 + rl0;
    const int cc0 = cb0 + (lane & 15);
#pragma unroll
    for (int mi = 0; mi < 4; ++mi)
#pragma unroll
        for (int rr = 0; rr < 4; ++rr) {
            const float sc = s_lds[rl0 + mi * 16 + rr];
#pragma unroll
            for (int ni = 0; ni < 4; ++ni)
                op[(r0 + mi * 16 + rr) * (size_t)ldc + cc0 + ni * 16] =
                    acc[mi][ni][rr] * sc;
        }
}

// ---------------------------------------------------------------------------
extern "C" void kernel_launch(void* const* d_in, const int* in_sizes, int n_in,
                              void* d_out, int out_size, void* d_ws, size_t ws_size,
                              hipStream_t stream) {
    const float* x   = (const float*)d_in[0];
    const float* lnw = (const float*)d_in[1];
    const float* wq  = (const float*)d_in[2];
    const float* wk  = (const float*)d_in[3];
    const float* wv  = (const float*)d_in[4];
    float* out = (float*)d_out;

    const int rows = in_sizes[0] / H;  // B*S = 32768

    __hip_bfloat16* Bt = (__hip_bfloat16*)d_ws;  // 1280*1024*2 = 2.62 MB

    k_wprep<<<320, 256, 0, stream>>>(wq, wk, wv, lnw, Bt);
    k_gemm<<<(rows / BM) * NTILES, 256, 0, stream>>>(x, Bt, out, rows);
}

// Round 13
// 144.405 us; speedup vs baseline: 1.3341x; 1.3341x over previous
//
#include <hip/hip_runtime.h>
#include <hip/hip_bf16.h>

typedef __attribute__((ext_vector_type(4))) float f32x4;
typedef __attribute__((ext_vector_type(8))) short bf16x8;

#define H 1024        // hidden / K
#define NTOT 1280     // nq*64 + nkv*64*2
#define BM 128
#define BN 256
#define BK 32
#define NKT2 32       // H / BK
#define NTILES 5      // NTOT / BN

static __device__ __forceinline__ unsigned short f2bf(float f) {
    __hip_bfloat16 b = __float2bfloat16(f);
    return __builtin_bit_cast(unsigned short, b);
}

#define GLOAD_LDS16(g, l)                                                     \
    __builtin_amdgcn_global_load_lds(                                         \
        (const __attribute__((address_space(1))) void*)(g),                   \
        (__attribute__((address_space(3))) void*)(l), 16, 0, 0)

// ---------------------------------------------------------------------------
// Kernel 1: RMSNorm rows of x (fp32) -> h (bf16). One wave per row.
// ---------------------------------------------------------------------------
__global__ __launch_bounds__(256) void k_rms(const float* __restrict__ x,
                                             __hip_bfloat16* __restrict__ h) {
    const int wave = threadIdx.x >> 6;
    const int lane = threadIdx.x & 63;
    const size_t row = (size_t)blockIdx.x * 4 + wave;

    const float4* xr = (const float4*)(x + row * H);
    float4 v[4];
    float ss = 0.f;
#pragma unroll
    for (int i = 0; i < 4; ++i) {
        v[i] = xr[lane + 64 * i];
        ss += v[i].x * v[i].x + v[i].y * v[i].y + v[i].z * v[i].z + v[i].w * v[i].w;
    }
#pragma unroll
    for (int o = 1; o < 64; o <<= 1) ss += __shfl_xor(ss, o);
    const float sc = rsqrtf(ss * (1.0f / H) + 1e-6f);

    ushort4* hr = (ushort4*)(h + row * H);
#pragma unroll
    for (int i = 0; i < 4; ++i) {
        ushort4 o4;
        o4.x = f2bf(v[i].x * sc);
        o4.y = f2bf(v[i].y * sc);
        o4.z = f2bf(v[i].z * sc);
        o4.w = f2bf(v[i].w * sc);
        hr[lane + 64 * i] = o4;
    }
}

// ---------------------------------------------------------------------------
// Kernel 2: Bt[n][k] = bf16((1+lnw[k]) * W[k][n]) via LDS transpose tile.
// ---------------------------------------------------------------------------
__global__ __launch_bounds__(256) void k_wprep(const float* __restrict__ wq,
                                               const float* __restrict__ wk,
                                               const float* __restrict__ wv,
                                               const float* __restrict__ lnw,
                                               __hip_bfloat16* __restrict__ Bt) {
    __shared__ float l[64][65];
    const int t = threadIdx.x;
    const int kt = blockIdx.x & 15;          // 16 k-tiles
    const int ntl = blockIdx.x >> 4;         // 20 n-tiles
    const int k0 = kt * 64, n0 = ntl * 64;
    const float* src; int ldn, nb;
    if (n0 < 1024)      { src = wq; ldn = 1024; nb = n0; }
    else if (n0 < 1152) { src = wk; ldn = 128;  nb = n0 - 1024; }
    else                { src = wv; ldn = 128;  nb = n0 - 1152; }
    const int nl = t & 63, kl = t >> 6;
#pragma unroll
    for (int i = 0; i < 16; ++i) {
        const int k = kl + i * 4;
        l[k][nl] = (1.0f + lnw[k0 + k]) * src[(size_t)(k0 + k) * ldn + nb + nl];
    }
    __syncthreads();
    const int k2 = t & 63, n2 = t >> 6;
#pragma unroll
    for (int i = 0; i < 16; ++i) {
        const int n = n2 + i * 4;
        Bt[(size_t)(n0 + n) * 1024 + k0 + k2] = __float2bfloat16(l[k2][n]);
    }
}

// ---------------------------------------------------------------------------
// Kernel 3: GEMM out[M][1280] = h[M][1024] @ Bt^T.
// R13: fatten the WAVE tile to cut LDS-read volume (the largest non-MFMA
// pipe term; every schedule lands at serial-sum of pipes, so minimize sum).
// Per-wave 128x64 (acc[8][4]=128 AGPR): LDS reads drop 94k->70k cyc/CU.
// 4 waves (1m x 4n), BM=128 BN=256 BK=32, ring-2 LDS 48KB -> 2 blocks/CU
// at 8 waves x ~238 regs <= 2048. Row-pair st-swizzle for the 64B-stride
// BK=32 tile: byte(r,kg) = (r>>1)*128 + ((((r&1)*4+kg) ^ ((r>>1)&7))<<4),
// applied BOTH sides (stage source pre-permuted + swizzled frag reads).
// 6 gloads/tile, seam vmcnt(6) (stage kt+1 forced, kt+2 stays in flight),
// 2 barriers/tile, setprio, XCD chunking nt-fastest, grid 1280.
// ---------------------------------------------------------------------------
__global__ __launch_bounds__(256, 2) void k_gemm(const __hip_bfloat16* __restrict__ A,
                                                 const __hip_bfloat16* __restrict__ Bt,
                                                 float* __restrict__ out, int rows) {
    __shared__ __align__(16) char smem[49152];  // 2 bufs x (A 8KB | B 16KB)

    const int tid = threadIdx.x;
    const int lane = tid & 63;
    const int wn = tid >> 6;   // 4 waves: cols wn*64, rows all 128

    // bijective XCD chunk swizzle (1280 % 8 == 0), nt fastest
    const int cpx = gridDim.x >> 3;                 // 160
    const int wg = (blockIdx.x & 7) * cpx + (blockIdx.x >> 3);
    const int nt = wg % NTILES;
    const int mt = wg / NTILES;
    const size_t m0 = (size_t)mt * BM;

    // ---- staging source pointers (dest slot d -> source (r,kg)):
    //      rp=d>>3; s=(d&7)^(rp&7); r=rp*2+(s>>2); kg=s&3
    const char* aSrc[2];
#pragma unroll
    for (int j = 0; j < 2; ++j) {
        const int d = tid + j * 256;
        const int rp = d >> 3, s = (d & 7) ^ (rp & 7);
        aSrc[j] = (const char*)A + (m0 + rp * 2 + (s >> 2)) * (size_t)(H * 2)
                  + (s & 3) * 16;
    }
    const char* bSrc[4];
#pragma unroll
    for (int j = 0; j < 4; ++j) {
        const int d = tid + j * 256;
        const int rp = d >> 3, s = (d & 7) ^ (rp & 7);
        bSrc[j] = (const char*)Bt + ((size_t)nt * BN + rp * 2 + (s >> 2)) * (size_t)(H * 2)
                  + (s & 3) * 16;
    }

#define STAGE(buf, kt)                                                        \
    {                                                                         \
        _Pragma("unroll") for (int j = 0; j < 2; ++j)                         \
            GLOAD_LDS16(aSrc[j] + (size_t)(kt) * 64,                          \
                        smem + (buf) * 24576 + (tid + j * 256) * 16);         \
        _Pragma("unroll") for (int j = 0; j < 4; ++j)                         \
            GLOAD_LDS16(bSrc[j] + (size_t)(kt) * 64,                          \
                        smem + (buf) * 24576 + 8192 + (tid + j * 256) * 16);  \
    }

    // ---- fragment read base (swizzled; same for A and B tiles) ----
    const int fb = ((lane & 15) >> 1) * 128
                 + (((((lane & 1) << 2) + (lane >> 4)) ^ ((lane & 15) >> 1)) << 4);
    const int bb = wn * 4096 + fb;

    f32x4 acc[8][4] = {};

#define TILE(cur, kt, DS, VM)                                                 \
    {                                                                         \
        const char* aL = smem + (cur) * 24576;                                \
        const char* bL = aL + 8192;                                           \
        asm volatile("s_waitcnt vmcnt(" VM ")" ::: "memory");                 \
        __builtin_amdgcn_s_barrier();                                         \
        bf16x8 af[4], bf_[4];                                                 \
        _Pragma("unroll") for (int mi = 0; mi < 4; ++mi)                      \
            af[mi] = *(const bf16x8*)(aL + fb + mi * 1024);                   \
        _Pragma("unroll") for (int ni = 0; ni < 4; ++ni)                      \
            bf_[ni] = *(const bf16x8*)(bL + bb + ni * 1024);                  \
        asm volatile("s_waitcnt lgkmcnt(0)" ::: "memory");                    \
        __builtin_amdgcn_s_setprio(1);                                        \
        _Pragma("unroll") for (int mi = 0; mi < 4; ++mi)                      \
            _Pragma("unroll") for (int ni = 0; ni < 4; ++ni)                  \
                acc[mi][ni] = __builtin_amdgcn_mfma_f32_16x16x32_bf16(        \
                    af[mi], bf_[ni], acc[mi][ni], 0, 0, 0);                   \
        __builtin_amdgcn_s_setprio(0);                                        \
        bf16x8 ag[4];                                                         \
        _Pragma("unroll") for (int mi = 0; mi < 4; ++mi)                      \
            ag[mi] = *(const bf16x8*)(aL + fb + (mi + 4) * 1024);             \
        asm volatile("s_waitcnt lgkmcnt(0)" ::: "memory");                    \
        __builtin_amdgcn_s_barrier();          /* all reads of buf done */    \
        __builtin_amdgcn_sched_barrier(0);                                    \
        if (DS) STAGE(cur, (kt) + 2);                                         \
        __builtin_amdgcn_s_setprio(1);                                        \
        _Pragma("unroll") for (int mi = 0; mi < 4; ++mi)                      \
            _Pragma("unroll") for (int ni = 0; ni < 4; ++ni)                  \
                acc[mi + 4][ni] = __builtin_amdgcn_mfma_f32_16x16x32_bf16(    \
                    ag[mi], bf_[ni], acc[mi + 4][ni], 0, 0, 0);               \
        __builtin_amdgcn_s_setprio(0);                                        \
    }

    // ---- prologue: stage k-steps 0 and 1 ----
    STAGE(0, 0);
    STAGE(1, 1);

    // ---- main loop: 32 k-steps, ring-2 ----
    for (int kt = 0; kt < NKT2 - 2; kt += 2) {
        TILE(0, kt, 1, "6");
        TILE(1, kt + 1, 1, "6");
    }
    TILE(0, NKT2 - 2, 0, "6");
    TILE(1, NKT2 - 1, 0, "0");

    // ---- epilogue: split q/k/v regions (wn*64 never straddles boundaries) ----
    const size_t QSZ = (size_t)rows * 1024;
    const size_t KSZ = (size_t)rows * 128;
    const int colg0 = nt * BN + wn * 64;
    float* op;
    int ldc, cb0;
    if (colg0 < 1024)      { op = out;             ldc = 1024; cb0 = colg0; }
    else if (colg0 < 1152) { op = out + QSZ;       ldc = 128;  cb0 = colg0 - 1024; }
    else                   { op = out + QSZ + KSZ; ldc = 128;  cb0 = colg0 - 1152; }

    const size_t r0 = m0 + ((lane >> 4) * 4);
    const int cc0 = cb0 + (lane & 15);
#pragma unroll
    for (int mi = 0; mi < 8; ++mi)
#pragma unroll
        for (int ni = 0; ni < 4; ++ni)
#pragma unroll
            for (int rr = 0; rr < 4; ++rr)
                op[(r0 + mi * 16 + rr) * (size_t)ldc + cc0 + ni * 16] = acc[mi][ni][rr];
}

// ---------------------------------------------------------------------------
extern "C" void kernel_launch(void* const* d_in, const int* in_sizes, int n_in,
                              void* d_out, int out_size, void* d_ws, size_t ws_size,
                              hipStream_t stream) {
    const float* x   = (const float*)d_in[0];
    const float* lnw = (const float*)d_in[1];
    const float* wq  = (const float*)d_in[2];
    const float* wk  = (const float*)d_in[3];
    const float* wv  = (const float*)d_in[4];
    float* out = (float*)d_out;

    const int rows = in_sizes[0] / H;  // B*S = 32768

    __hip_bfloat16* Bt = (__hip_bfloat16*)d_ws;                               // 2.62 MB
    __hip_bfloat16* h  = (__hip_bfloat16*)((char*)d_ws + (size_t)NTOT * H * 2);

    k_wprep<<<320, 256, 0, stream>>>(wq, wk, wv, lnw, Bt);
    k_rms<<<rows / 4, 256, 0, stream>>>(x, h);
    k_gemm<<<(rows / BM) * NTILES, 256, 0, stream>>>(h, Bt, out, rows);
}

// Round 15
// 143.261 us; speedup vs baseline: 1.3447x; 1.0080x over previous
//
#include <hip/hip_runtime.h>
#include <hip/hip_bf16.h>

typedef __attribute__((ext_vector_type(4))) float f32x4;
typedef __attribute__((ext_vector_type(8))) short bf16x8;

#define H 1024        // hidden / K
#define NTOT 1280     // nq*64 + nkv*64*2
#define BM 128
#define BN 128
#define BK 64
#define NKT 16        // H / BK
#define NTILES 10     // NTOT / BN

static __device__ __forceinline__ unsigned short f2bf(float f) {
    __hip_bfloat16 b = __float2bfloat16(f);
    return __builtin_bit_cast(unsigned short, b);
}

#define GLOAD_LDS16(g, l)                                                     \
    __builtin_amdgcn_global_load_lds(                                         \
        (const __attribute__((address_space(1))) void*)(g),                   \
        (__attribute__((address_space(3))) void*)(l), 16, 0, 0)

// ---------------------------------------------------------------------------
// Kernel 1: RMSNorm rows of x (fp32) -> h (bf16). One wave per row.
// (At BW roofline: 201 MB @ ~6.3 TB/s ~= 31 us measured.)
// ---------------------------------------------------------------------------
__global__ __launch_bounds__(256) void k_rms(const float* __restrict__ x,
                                             __hip_bfloat16* __restrict__ h) {
    const int wave = threadIdx.x >> 6;
    const int lane = threadIdx.x & 63;
    const size_t row = (size_t)blockIdx.x * 4 + wave;

    const float4* xr = (const float4*)(x + row * H);
    float4 v[4];
    float ss = 0.f;
#pragma unroll
    for (int i = 0; i < 4; ++i) {
        v[i] = xr[lane + 64 * i];
        ss += v[i].x * v[i].x + v[i].y * v[i].y + v[i].z * v[i].z + v[i].w * v[i].w;
    }
#pragma unroll
    for (int o = 1; o < 64; o <<= 1) ss += __shfl_xor(ss, o);
    const float sc = rsqrtf(ss * (1.0f / H) + 1e-6f);

    ushort4* hr = (ushort4*)(h + row * H);
#pragma unroll
    for (int i = 0; i < 4; ++i) {
        ushort4 o4;
        o4.x = f2bf(v[i].x * sc);
        o4.y = f2bf(v[i].y * sc);
        o4.z = f2bf(v[i].z * sc);
        o4.w = f2bf(v[i].w * sc);
        hr[lane + 64 * i] = o4;
    }
}

// ---------------------------------------------------------------------------
// Kernel 2: Bt[n][k] = bf16((1+lnw[k]) * W[k][n]) via LDS transpose tile.
// ---------------------------------------------------------------------------
__global__ __launch_bounds__(256) void k_wprep(const float* __restrict__ wq,
                                               const float* __restrict__ wk,
                                               const float* __restrict__ wv,
                                               const float* __restrict__ lnw,
                                               __hip_bfloat16* __restrict__ Bt) {
    __shared__ float l[64][65];
    const int t = threadIdx.x;
    const int kt = blockIdx.x & 15;          // 16 k-tiles
    const int ntl = blockIdx.x >> 4;         // 20 n-tiles
    const int k0 = kt * 64, n0 = ntl * 64;
    const float* src; int ldn, nb;
    if (n0 < 1024)      { src = wq; ldn = 1024; nb = n0; }
    else if (n0 < 1152) { src = wk; ldn = 128;  nb = n0 - 1024; }
    else                { src = wv; ldn = 128;  nb = n0 - 1152; }
    const int nl = t & 63, kl = t >> 6;
#pragma unroll
    for (int i = 0; i < 16; ++i) {
        const int k = kl + i * 4;
        l[k][nl] = (1.0f + lnw[k0 + k]) * src[(size_t)(k0 + k) * ldn + nb + nl];
    }
    __syncthreads();
    const int k2 = t & 63, n2 = t >> 6;
#pragma unroll
    for (int i = 0; i < 16; ++i) {
        const int n = n2 + i * 4;
        Bt[(size_t)(n0 + n) * 1024 + k0 + k2] = __float2bfloat16(l[k2][n]);
    }
}

// ---------------------------------------------------------------------------
// Kernel 3: GEMM out[M][1280] = h[M][1024] @ Bt^T.  (R10 config — session
// best — plus rule-#18 sched_barrier(0) fences after each ds-read-guarding
// lgkmcnt(0); R14's replay divergence was the un-fenced MFMA-hoist race.)
// 256-thr blocks (4 waves 2x2), BM=BN=128, 64KB LDS ring-2, acc[4][4]=64
// AGPR, ~88 VGPR -> 2 independent blocks/CU (epilogue of one overlaps
// K-loop of the other). 2 barriers/tile, counted vmcnt(8), T2 both-sides
// swizzle, XCD chunking nt-fastest, grid 2560 = 5 rounds.
// ---------------------------------------------------------------------------
__global__ __launch_bounds__(256, 2) void k_gemm(const __hip_bfloat16* __restrict__ A,
                                                 const __hip_bfloat16* __restrict__ Bt,
                                                 float* __restrict__ out, int rows) {
    __shared__ __align__(16) char smem[65536];  // 2 bufs x (A 16KB | B 16KB)

    const int tid = threadIdx.x;
    const int lane = tid & 63;
    const int wid = tid >> 6;
    const int wm = wid >> 1;   // 0..1 (64 rows each)
    const int wn = wid & 1;    // 0..1 (64 cols each)

    // bijective XCD chunk swizzle (2560 % 8 == 0), nt fastest
    const int cpx = gridDim.x >> 3;                 // 320
    const int wg = (blockIdx.x & 7) * cpx + (blockIdx.x >> 3);
    const int nt = wg % NTILES;
    const int mt = wg / NTILES;
    const size_t m0 = (size_t)mt * BM;

    // staging: thread t covers row (t>>3)+q*32 (q=0..3), 16B at (t&7)*16,
    // source col pre-swizzled by ((row&7)<<4)  (both-sides involution)
    const int r = tid >> 3;                         // 0..31
    const int cswz = ((tid & 7) * 16) ^ ((r & 7) << 4);
    const char* aG = (const char*)A + (m0 + r) * (size_t)(H * 2) + cswz;
    const char* bG = (const char*)Bt + ((size_t)nt * BN + r) * (size_t)(H * 2) + cswz;

#define STAGE(buf, kt)                                                        \
    {                                                                         \
        _Pragma("unroll") for (int q = 0; q < 4; ++q)                         \
            GLOAD_LDS16(aG + (size_t)(kt) * 128 + (size_t)q * 32 * (H * 2),   \
                        smem + (buf) * 32768 + q * 4096 + tid * 16);          \
        _Pragma("unroll") for (int q = 0; q < 4; ++q)                         \
            GLOAD_LDS16(bG + (size_t)(kt) * 128 + (size_t)q * 32 * (H * 2),   \
                        smem + (buf) * 32768 + 16384 + q * 4096 + tid * 16);  \
    }

    // fragment read addressing (swizzled)
    const int rowA = wm * 64 + (lane & 15);
    const int rowB = wn * 64 + (lane & 15);
    const int xm = (lane & 7) << 4;
    const int c0 = (((lane >> 4) * 16)) ^ xm;
    const int c1 = (64 + ((lane >> 4) * 16)) ^ xm;

    f32x4 acc[4][4] = {};

#define TILE(cur, kt, DS, VM)                                                 \
    {                                                                         \
        const char* aL = smem + (cur) * 32768;                                \
        const char* bL = aL + 16384;                                          \
        asm volatile("s_waitcnt vmcnt(" VM ")" ::: "memory");                 \
        __builtin_amdgcn_s_barrier();                                         \
        bf16x8 a0[4], b0[4];                                                  \
        _Pragma("unroll") for (int mi = 0; mi < 4; ++mi)                      \
            a0[mi] = *(const bf16x8*)(aL + (rowA + mi * 16) * 128 + c0);      \
        _Pragma("unroll") for (int ni = 0; ni < 4; ++ni)                      \
            b0[ni] = *(const bf16x8*)(bL + (rowB + ni * 16) * 128 + c0);      \
        asm volatile("s_waitcnt lgkmcnt(0)" ::: "memory");                    \
        __builtin_amdgcn_sched_barrier(0);    /* rule #18: fence MFMA hoist */\
        __builtin_amdgcn_s_setprio(1);                                        \
        _Pragma("unroll") for (int mi = 0; mi < 4; ++mi)                      \
            _Pragma("unroll") for (int ni = 0; ni < 4; ++ni)                  \
                acc[mi][ni] = __builtin_amdgcn_mfma_f32_16x16x32_bf16(        \
                    a0[mi], b0[ni], acc[mi][ni], 0, 0, 0);                    \
        __builtin_amdgcn_s_setprio(0);                                        \
        bf16x8 a1[4], b1[4];                                                  \
        _Pragma("unroll") for (int mi = 0; mi < 4; ++mi)                      \
            a1[mi] = *(const bf16x8*)(aL + (rowA + mi * 16) * 128 + c1);      \
        _Pragma("unroll") for (int ni = 0; ni < 4; ++ni)                      \
            b1[ni] = *(const bf16x8*)(bL + (rowB + ni * 16) * 128 + c1);      \
        asm volatile("s_waitcnt lgkmcnt(0)" ::: "memory");                    \
        __builtin_amdgcn_sched_barrier(0);                                    \
        __builtin_amdgcn_s_barrier();                                         \
        __builtin_amdgcn_sched_barrier(0);                                    \
        if (DS) STAGE(cur, (kt) + 2);                                         \
        __builtin_amdgcn_s_setprio(1);                                        \
        _Pragma("unroll") for (int mi = 0; mi < 4; ++mi)                      \
            _Pragma("unroll") for (int ni = 0; ni < 4; ++ni)                  \
                acc[mi][ni] = __builtin_amdgcn_mfma_f32_16x16x32_bf16(        \
                    a1[mi], b1[ni], acc[mi][ni], 0, 0, 0);                    \
        __builtin_amdgcn_s_setprio(0);                                        \
    }

    // prologue: stage tiles 0 and 1
    STAGE(0, 0);
    STAGE(1, 1);

    // main loop: ring-2, 2 barriers/tile, loads never drained mid-loop
    for (int kt = 0; kt < NKT - 4; kt += 2) {
        TILE(0, kt, 1, "8");
        TILE(1, kt + 1, 1, "8");
    }
    TILE(0, NKT - 4, 1, "8");   // stages tile 14
    TILE(1, NKT - 3, 1, "8");   // stages tile 15
    TILE(0, NKT - 2, 0, "8");
    TILE(1, NKT - 1, 0, "0");

    // epilogue: split q/k/v regions (wn*64 chunks never straddle boundaries)
    const size_t QSZ = (size_t)rows * 1024;
    const size_t KSZ = (size_t)rows * 128;
    const int colg0 = nt * BN + wn * 64;
    float* op;
    int ldc, cb0;
    if (colg0 < 1024)      { op = out;             ldc = 1024; cb0 = colg0; }
    else if (colg0 < 1152) { op = out + QSZ;       ldc = 128;  cb0 = colg0 - 1024; }
    else                   { op = out + QSZ + KSZ; ldc = 128;  cb0 = colg0 - 1152; }

    const size_t r0 = m0 + wm * 64 + ((lane >> 4) * 4);
    const int cc0 = cb0 + (lane & 15);
#pragma unroll
    for (int mi = 0; mi < 4; ++mi)
#pragma unroll
        for (int ni = 0; ni < 4; ++ni)
#pragma unroll
            for (int rr = 0; rr < 4; ++rr)
                op[(r0 + mi * 16 + rr) * (size_t)ldc + cc0 + ni * 16] = acc[mi][ni][rr];
}

// ---------------------------------------------------------------------------
extern "C" void kernel_launch(void* const* d_in, const int* in_sizes, int n_in,
                              void* d_out, int out_size, void* d_ws, size_t ws_size,
                              hipStream_t stream) {
    const float* x   = (const float*)d_in[0];
    const float* lnw = (const float*)d_in[1];
    const float* wq  = (const float*)d_in[2];
    const float* wk  = (const float*)d_in[3];
    const float* wv  = (const float*)d_in[4];
    float* out = (float*)d_out;

    const int rows = in_sizes[0] / H;  // B*S = 32768

    __hip_bfloat16* Bt = (__hip_bfloat16*)d_ws;                               // 2.62 MB
    __hip_bfloat16* h  = (__hip_bfloat16*)((char*)d_ws + (size_t)NTOT * H * 2);

    k_wprep<<<320, 256, 0, stream>>>(wq, wk, wv, lnw, Bt);
    k_rms<<<rows / 4, 256, 0, stream>>>(x, h);
    k_gemm<<<(rows / BM) * NTILES, 256, 0, stream>>>(h, Bt, out, rows);
}

// Round 16
// 140.193 us; speedup vs baseline: 1.3742x; 1.0219x over previous
//
#include <hip/hip_runtime.h>
#include <hip/hip_bf16.h>

typedef __attribute__((ext_vector_type(4))) float f32x4;
typedef __attribute__((ext_vector_type(8))) short bf16x8;

#define H 1024        // hidden / K
#define NTOT 1280     // nq*64 + nkv*64*2
#define BM 128
#define BN 128
#define BK 64
#define NKT 16        // H / BK
#define NTILES 10     // NTOT / BN

static __device__ __forceinline__ unsigned short f2bf(float f) {
    __hip_bfloat16 b = __float2bfloat16(f);
    return __builtin_bit_cast(unsigned short, b);
}

#define GLOAD_LDS16(g, l)                                                     \
    __builtin_amdgcn_global_load_lds(                                         \
        (const __attribute__((address_space(1))) void*)(g),                   \
        (__attribute__((address_space(3))) void*)(l), 16, 0, 0)

// ---------------------------------------------------------------------------
// Kernel 1: RMSNorm rows of x (fp32) -> h (bf16). One wave per row.
// (BW roofline: 201 MB @ ~6.4 TB/s ~= 31 us measured.)
// ---------------------------------------------------------------------------
__global__ __launch_bounds__(256) void k_rms(const float* __restrict__ x,
                                             __hip_bfloat16* __restrict__ h) {
    const int wave = threadIdx.x >> 6;
    const int lane = threadIdx.x & 63;
    const size_t row = (size_t)blockIdx.x * 4 + wave;

    const float4* xr = (const float4*)(x + row * H);
    float4 v[4];
    float ss = 0.f;
#pragma unroll
    for (int i = 0; i < 4; ++i) {
        v[i] = xr[lane + 64 * i];
        ss += v[i].x * v[i].x + v[i].y * v[i].y + v[i].z * v[i].z + v[i].w * v[i].w;
    }
#pragma unroll
    for (int o = 1; o < 64; o <<= 1) ss += __shfl_xor(ss, o);
    const float sc = rsqrtf(ss * (1.0f / H) + 1e-6f);

    ushort4* hr = (ushort4*)(h + row * H);
#pragma unroll
    for (int i = 0; i < 4; ++i) {
        ushort4 o4;
        o4.x = f2bf(v[i].x * sc);
        o4.y = f2bf(v[i].y * sc);
        o4.z = f2bf(v[i].z * sc);
        o4.w = f2bf(v[i].w * sc);
        hr[lane + 64 * i] = o4;
    }
}

// ---------------------------------------------------------------------------
// Kernel 2: Bt[n][k] = bf16((1+lnw[k]) * W[k][n]) via LDS transpose tile.
// ---------------------------------------------------------------------------
__global__ __launch_bounds__(256) void k_wprep(const float* __restrict__ wq,
                                               const float* __restrict__ wk,
                                               const float* __restrict__ wv,
                                               const float* __restrict__ lnw,
                                               __hip_bfloat16* __restrict__ Bt) {
    __shared__ float l[64][65];
    const int t = threadIdx.x;
    const int kt = blockIdx.x & 15;          // 16 k-tiles
    const int ntl = blockIdx.x >> 4;         // 20 n-tiles
    const int k0 = kt * 64, n0 = ntl * 64;
    const float* src; int ldn, nb;
    if (n0 < 1024)      { src = wq; ldn = 1024; nb = n0; }
    else if (n0 < 1152) { src = wk; ldn = 128;  nb = n0 - 1024; }
    else                { src = wv; ldn = 128;  nb = n0 - 1152; }
    const int nl = t & 63, kl = t >> 6;
#pragma unroll
    for (int i = 0; i < 16; ++i) {
        const int k = kl + i * 4;
        l[k][nl] = (1.0f + lnw[k0 + k]) * src[(size_t)(k0 + k) * ldn + nb + nl];
    }
    __syncthreads();
    const int k2 = t & 63, n2 = t >> 6;
#pragma unroll
    for (int i = 0; i < 16; ++i) {
        const int n = n2 + i * 4;
        Bt[(size_t)(n0 + n) * 1024 + k0 + k2] = __float2bfloat16(l[k2][n]);
    }
}

// ---------------------------------------------------------------------------
// Kernel 3: GEMM out[M][1280] = h[M][1024] @ Bt^T.
// R16 = R15 (session-best R10 config, race-hardened) with ONE deletion:
// no inline lgkmcnt(0) before MFMA group 0. R15's cycle audit: per K-tile
// per CU, MFMA 1242 cyc + LDS 1790 cyc ~= observed 3200 -> pipes fully
// SERIALIZED; the hand-written full lgkm drain before each MFMA cluster
// forbade the compiler's partial-wait overlap (lgkmcnt(4/3/1/0)) that lets
// group-0 MFMAs run under group-1 ds_reads. Compiler now owns the
// ds_read->MFMA ordering inside the tile (register deps). Kept: seam
// vmcnt(8)+barrier+fence (buffer validity), lgkm0+fence before mid-tile
// barrier (all waves drain own reads before any STAGE overwrites the
// buffer; rule #18), 2 blocks/CU, T2 swizzle, XCD chunking, grid 2560.
// ---------------------------------------------------------------------------
__global__ __launch_bounds__(256, 2) void k_gemm(const __hip_bfloat16* __restrict__ A,
                                                 const __hip_bfloat16* __restrict__ Bt,
                                                 float* __restrict__ out, int rows) {
    __shared__ __align__(16) char smem[65536];  // 2 bufs x (A 16KB | B 16KB)

    const int tid = threadIdx.x;
    const int lane = tid & 63;
    const int wid = tid >> 6;
    const int wm = wid >> 1;   // 0..1 (64 rows each)
    const int wn = wid & 1;    // 0..1 (64 cols each)

    // bijective XCD chunk swizzle (2560 % 8 == 0), nt fastest
    const int cpx = gridDim.x >> 3;                 // 320
    const int wg = (blockIdx.x & 7) * cpx + (blockIdx.x >> 3);
    const int nt = wg % NTILES;
    const int mt = wg / NTILES;
    const size_t m0 = (size_t)mt * BM;

    // staging: thread t covers row (t>>3)+q*32 (q=0..3), 16B at (t&7)*16,
    // source col pre-swizzled by ((row&7)<<4)  (both-sides involution)
    const int r = tid >> 3;                         // 0..31
    const int cswz = ((tid & 7) * 16) ^ ((r & 7) << 4);
    const char* aG = (const char*)A + (m0 + r) * (size_t)(H * 2) + cswz;
    const char* bG = (const char*)Bt + ((size_t)nt * BN + r) * (size_t)(H * 2) + cswz;

#define STAGE(buf, kt)                                                        \
    {                                                                         \
        _Pragma("unroll") for (int q = 0; q < 4; ++q)                         \
            GLOAD_LDS16(aG + (size_t)(kt) * 128 + (size_t)q * 32 * (H * 2),   \
                        smem + (buf) * 32768 + q * 4096 + tid * 16);          \
        _Pragma("unroll") for (int q = 0; q < 4; ++q)                         \
            GLOAD_LDS16(bG + (size_t)(kt) * 128 + (size_t)q * 32 * (H * 2),   \
                        smem + (buf) * 32768 + 16384 + q * 4096 + tid * 16);  \
    }

    // fragment read addressing (swizzled)
    const int rowA = wm * 64 + (lane & 15);
    const int rowB = wn * 64 + (lane & 15);
    const int xm = (lane & 7) << 4;
    const int c0 = (((lane >> 4) * 16)) ^ xm;
    const int c1 = (64 + ((lane >> 4) * 16)) ^ xm;

    f32x4 acc[4][4] = {};

#define TILE(cur, kt, DS, VM)                                                 \
    {                                                                         \
        const char* aL = smem + (cur) * 32768;                                \
        const char* bL = aL + 16384;                                          \
        asm volatile("s_waitcnt vmcnt(" VM ")" ::: "memory");                 \
        __builtin_amdgcn_s_barrier();                                         \
        __builtin_amdgcn_sched_barrier(0);                                    \
        bf16x8 a0[4], b0[4];                                                  \
        _Pragma("unroll") for (int mi = 0; mi < 4; ++mi)                      \
            a0[mi] = *(const bf16x8*)(aL + (rowA + mi * 16) * 128 + c0);      \
        _Pragma("unroll") for (int ni = 0; ni < 4; ++ni)                      \
            b0[ni] = *(const bf16x8*)(bL + (rowB + ni * 16) * 128 + c0);      \
        /* NO manual lgkm drain here: compiler emits partial lgkmcnt so     */\
        /* group-0 MFMAs overlap group-1 ds_reads (the R15 serialization).  */\
        bf16x8 a1[4], b1[4];                                                  \
        _Pragma("unroll") for (int mi = 0; mi < 4; ++mi)                      \
            a1[mi] = *(const bf16x8*)(aL + (rowA + mi * 16) * 128 + c1);      \
        _Pragma("unroll") for (int ni = 0; ni < 4; ++ni)                      \
            b1[ni] = *(const bf16x8*)(bL + (rowB + ni * 16) * 128 + c1);      \
        __builtin_amdgcn_s_setprio(1);                                        \
        _Pragma("unroll") for (int mi = 0; mi < 4; ++mi)                      \
            _Pragma("unroll") for (int ni = 0; ni < 4; ++ni)                  \
                acc[mi][ni] = __builtin_amdgcn_mfma_f32_16x16x32_bf16(        \
                    a0[mi], b0[ni], acc[mi][ni], 0, 0, 0);                    \
        __builtin_amdgcn_s_setprio(0);                                        \
        asm volatile("s_waitcnt lgkmcnt(0)" ::: "memory");                    \
        __builtin_amdgcn_sched_barrier(0);    /* rule #18 fence */            \
        __builtin_amdgcn_s_barrier();                                         \
        __builtin_amdgcn_sched_barrier(0);                                    \
        if (DS) STAGE(cur, (kt) + 2);                                         \
        __builtin_amdgcn_s_setprio(1);                                        \
        _Pragma("unroll") for (int mi = 0; mi < 4; ++mi)                      \
            _Pragma("unroll") for (int ni = 0; ni < 4; ++ni)                  \
                acc[mi][ni] = __builtin_amdgcn_mfma_f32_16x16x32_bf16(        \
                    a1[mi], b1[ni], acc[mi][ni], 0, 0, 0);                    \
        __builtin_amdgcn_s_setprio(0);                                        \
    }

    // prologue: stage tiles 0 and 1
    STAGE(0, 0);
    STAGE(1, 1);

    // main loop: ring-2, 2 barriers/tile, loads never drained mid-loop
    for (int kt = 0; kt < NKT - 4; kt += 2) {
        TILE(0, kt, 1, "8");
        TILE(1, kt + 1, 1, "8");
    }
    TILE(0, NKT - 4, 1, "8");   // stages tile 14
    TILE(1, NKT - 3, 1, "8");   // stages tile 15
    TILE(0, NKT - 2, 0, "8");
    TILE(1, NKT - 1, 0, "0");

    // epilogue: split q/k/v regions (wn*64 chunks never straddle boundaries)
    const size_t QSZ = (size_t)rows * 1024;
    const size_t KSZ = (size_t)rows * 128;
    const int colg0 = nt * BN + wn * 64;
    float* op;
    int ldc, cb0;
    if (colg0 < 1024)      { op = out;             ldc = 1024; cb0 = colg0; }
    else if (colg0 < 1152) { op = out + QSZ;       ldc = 128;  cb0 = colg0 - 1024; }
    else                   { op = out + QSZ + KSZ; ldc = 128;  cb0 = colg0 - 1152; }

    const size_t r0 = m0 + wm * 64 + ((lane >> 4) * 4);
    const int cc0 = cb0 + (lane & 15);
#pragma unroll
    for (int mi = 0; mi < 4; ++mi)
#pragma unroll
        for (int ni = 0; ni < 4; ++ni)
#pragma unroll
            for (int rr = 0; rr < 4; ++rr)
                op[(r0 + mi * 16 + rr) * (size_t)ldc + cc0 + ni * 16] = acc[mi][ni][rr];
}

// ---------------------------------------------------------------------------
extern "C" void kernel_launch(void* const* d_in, const int* in_sizes, int n_in,
                              void* d_out, int out_size, void* d_ws, size_t ws_size,
                              hipStream_t stream) {
    const float* x   = (const float*)d_in[0];
    const float* lnw = (const float*)d_in[1];
    const float* wq  = (const float*)d_in[2];
    const float* wk  = (const float*)d_in[3];
    const float* wv  = (const float*)d_in[4];
    float* out = (float*)d_out;

    const int rows = in_sizes[0] / H;  // B*S = 32768

    __hip_bfloat16* Bt = (__hip_bfloat16*)d_ws;                               // 2.62 MB
    __hip_bfloat16* h  = (__hip_bfloat16*)((char*)d_ws + (size_t)NTOT * H * 2);

    k_wprep<<<320, 256, 0, stream>>>(wq, wk, wv, lnw, Bt);
    k_rms<<<rows / 4, 256, 0, stream>>>(x, h);
    k_gemm<<<(rows / BM) * NTILES, 256, 0, stream>>>(h, Bt, out, rows);
}

// Round 17
// 135.152 us; speedup vs baseline: 1.4254x; 1.0373x over previous
//
#include <hip/hip_runtime.h>
#include <hip/hip_bf16.h>

typedef __attribute__((ext_vector_type(4))) float f32x4;
typedef __attribute__((ext_vector_type(8))) short bf16x8;

#define H 1024        // hidden / K
#define NTOT 1280     // nq*64 + nkv*64*2
#define BM 128
#define BN 128
#define BK 64
#define NKT 16        // H / BK
#define NTILES 10     // NTOT / BN

static __device__ __forceinline__ unsigned short f2bf(float f) {
    __hip_bfloat16 b = __float2bfloat16(f);
    return __builtin_bit_cast(unsigned short, b);
}

#define GLOAD_LDS16(g, l)                                                     \
    __builtin_amdgcn_global_load_lds(                                         \
        (const __attribute__((address_space(1))) void*)(g),                   \
        (__attribute__((address_space(3))) void*)(l), 16, 0, 0)

// ---------------------------------------------------------------------------
// Kernel 1 (merged prologue): blocks [0, rows/4) do RMSNorm (one wave per
// row, 4 rows/block); blocks [rows/4, rows/4+320) build the transposed fused
// weight Bt[n][k] = bf16((1+lnw[k]) * W[k][n]). Merging removes one launch
// boundary and lets the 320 wprep blocks run concurrently with rms instead
// of serializing after it.
// ---------------------------------------------------------------------------
__global__ __launch_bounds__(256) void k_pre(const float* __restrict__ x,
                                             const float* __restrict__ wq,
                                             const float* __restrict__ wk,
                                             const float* __restrict__ wv,
                                             const float* __restrict__ lnw,
                                             __hip_bfloat16* __restrict__ h,
                                             __hip_bfloat16* __restrict__ Bt,
                                             int nrms) {
    __shared__ float l[64][65];
    const int t = threadIdx.x;

    if ((int)blockIdx.x < nrms) {
        // ---- RMSNorm: x (fp32) -> h (bf16), (1+lnw) folded into weights ----
        const int wave = t >> 6;
        const int lane = t & 63;
        const size_t row = (size_t)blockIdx.x * 4 + wave;

        const float4* xr = (const float4*)(x + row * H);
        float4 v[4];
        float ss = 0.f;
#pragma unroll
        for (int i = 0; i < 4; ++i) {
            v[i] = xr[lane + 64 * i];
            ss += v[i].x * v[i].x + v[i].y * v[i].y + v[i].z * v[i].z + v[i].w * v[i].w;
        }
#pragma unroll
        for (int o = 1; o < 64; o <<= 1) ss += __shfl_xor(ss, o);
        const float sc = rsqrtf(ss * (1.0f / H) + 1e-6f);

        ushort4* hr = (ushort4*)(h + row * H);
#pragma unroll
        for (int i = 0; i < 4; ++i) {
            ushort4 o4;
            o4.x = f2bf(v[i].x * sc);
            o4.y = f2bf(v[i].y * sc);
            o4.z = f2bf(v[i].z * sc);
            o4.w = f2bf(v[i].w * sc);
            hr[lane + 64 * i] = o4;
        }
    } else {
        // ---- weight prep via LDS transpose tile ----
        const int b = (int)blockIdx.x - nrms;     // 0..319
        const int kt = b & 15;                    // 16 k-tiles
        const int ntl = b >> 4;                   // 20 n-tiles
        const int k0 = kt * 64, n0 = ntl * 64;
        const float* src; int ldn, nb;
        if (n0 < 1024)      { src = wq; ldn = 1024; nb = n0; }
        else if (n0 < 1152) { src = wk; ldn = 128;  nb = n0 - 1024; }
        else                { src = wv; ldn = 128;  nb = n0 - 1152; }
        const int nl = t & 63, kl = t >> 6;
#pragma unroll
        for (int i = 0; i < 16; ++i) {
            const int k = kl + i * 4;
            l[k][nl] = (1.0f + lnw[k0 + k]) * src[(size_t)(k0 + k) * ldn + nb + nl];
        }
        __syncthreads();
        const int k2 = t & 63, n2 = t >> 6;
#pragma unroll
        for (int i = 0; i < 16; ++i) {
            const int n = n2 + i * 4;
            Bt[(size_t)(n0 + n) * 1024 + k0 + k2] = __float2bfloat16(l[k2][n]);
        }
    }
}

// ---------------------------------------------------------------------------
// Kernel 2: GEMM out[M][1280] = h[M][1024] @ Bt^T.  (R16 — session best.)
// 256-thr blocks (4 waves 2x2), BM=BN=128, 64KB LDS ring-2, acc[4][4]=64
// AGPR -> 2 independent blocks/CU. 2 barriers/tile, counted vmcnt(8), T2
// both-sides swizzle, XCD chunking nt-fastest, grid 2560 = 5 rounds.
// Rule-#18 fence retained before the mid-tile barrier.
// ---------------------------------------------------------------------------
__global__ __launch_bounds__(256, 2) void k_gemm(const __hip_bfloat16* __restrict__ A,
                                                 const __hip_bfloat16* __restrict__ Bt,
                                                 float* __restrict__ out, int rows) {
    __shared__ __align__(16) char smem[65536];  // 2 bufs x (A 16KB | B 16KB)

    const int tid = threadIdx.x;
    const int lane = tid & 63;
    const int wid = tid >> 6;
    const int wm = wid >> 1;   // 0..1 (64 rows each)
    const int wn = wid & 1;    // 0..1 (64 cols each)

    // bijective XCD chunk swizzle (2560 % 8 == 0), nt fastest
    const int cpx = gridDim.x >> 3;                 // 320
    const int wg = (blockIdx.x & 7) * cpx + (blockIdx.x >> 3);
    const int nt = wg % NTILES;
    const int mt = wg / NTILES;
    const size_t m0 = (size_t)mt * BM;

    // staging: thread t covers row (t>>3)+q*32 (q=0..3), 16B at (t&7)*16,
    // source col pre-swizzled by ((row&7)<<4)  (both-sides involution)
    const int r = tid >> 3;                         // 0..31
    const int cswz = ((tid & 7) * 16) ^ ((r & 7) << 4);
    const char* aG = (const char*)A + (m0 + r) * (size_t)(H * 2) + cswz;
    const char* bG = (const char*)Bt + ((size_t)nt * BN + r) * (size_t)(H * 2) + cswz;

#define STAGE(buf, kt)                                                        \
    {                                                                         \
        _Pragma("unroll") for (int q = 0; q < 4; ++q)                         \
            GLOAD_LDS16(aG + (size_t)(kt) * 128 + (size_t)q * 32 * (H * 2),   \
                        smem + (buf) * 32768 + q * 4096 + tid * 16);          \
        _Pragma("unroll") for (int q = 0; q < 4; ++q)                         \
            GLOAD_LDS16(bG + (size_t)(kt) * 128 + (size_t)q * 32 * (H * 2),   \
                        smem + (buf) * 32768 + 16384 + q * 4096 + tid * 16);  \
    }

    // fragment read addressing (swizzled)
    const int rowA = wm * 64 + (lane & 15);
    const int rowB = wn * 64 + (lane & 15);
    const int xm = (lane & 7) << 4;
    const int c0 = (((lane >> 4) * 16)) ^ xm;
    const int c1 = (64 + ((lane >> 4) * 16)) ^ xm;

    f32x4 acc[4][4] = {};

#define TILE(cur, kt, DS, VM)                                                 \
    {                                                                         \
        const char* aL = smem + (cur) * 32768;                                \
        const char* bL = aL + 16384;                                          \
        asm volatile("s_waitcnt vmcnt(" VM ")" ::: "memory");                 \
        __builtin_amdgcn_s_barrier();                                         \
        __builtin_amdgcn_sched_barrier(0);                                    \
        bf16x8 a0[4], b0[4];                                                  \
        _Pragma("unroll") for (int mi = 0; mi < 4; ++mi)                      \
            a0[mi] = *(const bf16x8*)(aL + (rowA + mi * 16) * 128 + c0);      \
        _Pragma("unroll") for (int ni = 0; ni < 4; ++ni)                      \
            b0[ni] = *(const bf16x8*)(bL + (rowB + ni * 16) * 128 + c0);      \
        bf16x8 a1[4], b1[4];                                                  \
        _Pragma("unroll") for (int mi = 0; mi < 4; ++mi)                      \
            a1[mi] = *(const bf16x8*)(aL + (rowA + mi * 16) * 128 + c1);      \
        _Pragma("unroll") for (int ni = 0; ni < 4; ++ni)                      \
            b1[ni] = *(const bf16x8*)(bL + (rowB + ni * 16) * 128 + c1);      \
        __builtin_amdgcn_s_setprio(1);                                        \
        _Pragma("unroll") for (int mi = 0; mi < 4; ++mi)                      \
            _Pragma("unroll") for (int ni = 0; ni < 4; ++ni)                  \
                acc[mi][ni] = __builtin_amdgcn_mfma_f32_16x16x32_bf16(        \
                    a0[mi], b0[ni], acc[mi][ni], 0, 0, 0);                    \
        __builtin_amdgcn_s_setprio(0);                                        \
        asm volatile("s_waitcnt lgkmcnt(0)" ::: "memory");                    \
        __builtin_amdgcn_sched_barrier(0);    /* rule #18 fence */            \
        __builtin_amdgcn_s_barrier();                                         \
        __builtin_amdgcn_sched_barrier(0);                                    \
        if (DS) STAGE(cur, (kt) + 2);                                         \
        __builtin_amdgcn_s_setprio(1);                                        \
        _Pragma("unroll") for (int mi = 0; mi < 4; ++mi)                      \
            _Pragma("unroll") for (int ni = 0; ni < 4; ++ni)                  \
                acc[mi][ni] = __builtin_amdgcn_mfma_f32_16x16x32_bf16(        \
                    a1[mi], b1[ni], acc[mi][ni], 0, 0, 0);                    \
        __builtin_amdgcn_s_setprio(0);                                        \
    }

    // prologue: stage tiles 0 and 1
    STAGE(0, 0);
    STAGE(1, 1);

    // main loop: ring-2, 2 barriers/tile, loads never drained mid-loop
    for (int kt = 0; kt < NKT - 4; kt += 2) {
        TILE(0, kt, 1, "8");
        TILE(1, kt + 1, 1, "8");
    }
    TILE(0, NKT - 4, 1, "8");   // stages tile 14
    TILE(1, NKT - 3, 1, "8");   // stages tile 15
    TILE(0, NKT - 2, 0, "8");
    TILE(1, NKT - 1, 0, "0");

    // epilogue: split q/k/v regions (wn*64 chunks never straddle boundaries)
    const size_t QSZ = (size_t)rows * 1024;
    const size_t KSZ = (size_t)rows * 128;
    const int colg0 = nt * BN + wn * 64;
    float* op;
    int ldc, cb0;
    if (colg0 < 1024)      { op = out;             ldc = 1024; cb0 = colg0; }
    else if (colg0 < 1152) { op = out + QSZ;       ldc = 128;  cb0 = colg0 - 1024; }
    else                   { op = out + QSZ + KSZ; ldc = 128;  cb0 = colg0 - 1152; }

    const size_t r0 = m0 + wm * 64 + ((lane >> 4) * 4);
    const int cc0 = cb0 + (lane & 15);
#pragma unroll
    for (int mi = 0; mi < 4; ++mi)
#pragma unroll
        for (int ni = 0; ni < 4; ++ni)
#pragma unroll
            for (int rr = 0; rr < 4; ++rr)
                op[(r0 + mi * 16 + rr) * (size_t)ldc + cc0 + ni * 16] = acc[mi][ni][rr];
}

// ---------------------------------------------------------------------------
extern "C" void kernel_launch(void* const* d_in, const int* in_sizes, int n_in,
                              void* d_out, int out_size, void* d_ws, size_t ws_size,
                              hipStream_t stream) {
    const float* x   = (const float*)d_in[0];
    const float* lnw = (const float*)d_in[1];
    const float* wq  = (const float*)d_in[2];
    const float* wk  = (const float*)d_in[3];
    const float* wv  = (const float*)d_in[4];
    float* out = (float*)d_out;

    const int rows = in_sizes[0] / H;  // B*S = 32768

    __hip_bfloat16* Bt = (__hip_bfloat16*)d_ws;                               // 2.62 MB
    __hip_bfloat16* h  = (__hip_bfloat16*)((char*)d_ws + (size_t)NTOT * H * 2);

    const int nrms = rows / 4;  // 8192
    k_pre<<<nrms + 320, 256, 0, stream>>>(x, wq, wk, wv, lnw, h, Bt, nrms);
    k_gemm<<<(rows / BM) * NTILES, 256, 0, stream>>>(h, Bt, out, rows);
}